// Round 1
// baseline (167.717 us; speedup 1.0000x reference)
//
#include <hip/hip_runtime.h>
#include <hip/hip_bf16.h>

#define Bn 128
#define Nn 8192
#define Hn 128
#define ROWS 64
#define JOUT 62
#define NBJ 133   // ceil(8192/62)

typedef __attribute__((ext_vector_type(8))) short short8;
typedef __attribute__((ext_vector_type(4))) float f32x4;

__device__ __forceinline__ unsigned int f2bf(float x) {
    union { float f; unsigned u; } v; v.f = x;
    return (v.u + 0x7fffu + ((v.u >> 16) & 1u)) >> 16;
}
__device__ __forceinline__ float swish(float x) {
    return x * __builtin_amdgcn_rcpf(1.0f + __expf(-x));
}

// Pre-pack W2/W3 as bf16 MFMA B-fragments into ws.
// ws2: frag F = ((w*2+ct)*4+ks), lane l, elem e:
//   col = w*32+ct*16+(l&15), k = ks*32 + (l>>4)*8 + e  -> W2[k][col]
// ws3 (offset 16384 ushorts): frag ks, lane l, elem e:
//   col = l&15 (<9 else 0), k = ks*32+(l>>4)*8+e       -> W3[k][col]
__global__ void prep_kernel(const float* __restrict__ W2, const float* __restrict__ W3,
                            unsigned short* __restrict__ ws)
{
    int tid = blockIdx.x * 256 + threadIdx.x;
    if (tid < 16384) {
        int F = tid >> 9, rem = tid & 511;
        int l = rem >> 3, e = rem & 7;
        int w = F >> 3, ct = (F >> 2) & 1, ks = F & 3;
        int col = w * 32 + ct * 16 + (l & 15);
        int k = ks * 32 + (l >> 4) * 8 + e;
        ws[tid] = (unsigned short)f2bf(W2[k * Hn + col]);
    } else if (tid < 18432) {
        int t2 = tid - 16384;
        int ks = t2 >> 9, rem = t2 & 511;
        int l = rem >> 3, e = rem & 7;
        int c = l & 15;
        int k = ks * 32 + (l >> 4) * 8 + e;
        float v = (c < 9) ? W3[k * 9 + c] : 0.0f;
        ws[tid] = (unsigned short)f2bf(v);
    }
}

__global__ __launch_bounds__(256, 2) void fused_kernel(
    const float* __restrict__ y, const float* __restrict__ W1,
    const float* __restrict__ b1, const float* __restrict__ b2,
    const float* __restrict__ b3, const unsigned short* __restrict__ ws,
    float* __restrict__ out)
{
    __shared__ float t_lds[ROWS][10];
    __shared__ float W1_lds[9 * 128];
    __shared__ char h1_raw[ROWS * 256];   // bf16, XOR-swizzled rows
    __shared__ char h2_raw[ROWS * 256];   // bf16, XOR-swizzled rows
    __shared__ float f_lds[ROWS][12];

    const int tid = threadIdx.x;
    const int lane = tid & 63;
    const int w = tid >> 6;
    const int bj = blockIdx.x;
    const int b = blockIdx.y;
    const int j0 = bj * JOUT;

    const int r15 = lane & 15, g = lane >> 4;

    // W2/W3 B-fragments -> registers (coalesced 16B/lane from ws, L2-resident)
    const short8* wsf = (const short8*)ws;
    short8 b2f[2][4], b3f[4];
    #pragma unroll
    for (int ct = 0; ct < 2; ++ct)
        #pragma unroll
        for (int ks = 0; ks < 4; ++ks)
            b2f[ct][ks] = wsf[((w * 2 + ct) * 4 + ks) * 64 + lane];
    #pragma unroll
    for (int ks = 0; ks < 4; ++ks)
        b3f[ks] = wsf[2048 + ks * 64 + lane];

    float b2v[2];
    b2v[0] = b2[w * 32 + r15];
    b2v[1] = b2[w * 32 + 16 + r15];
    float b3v = (r15 < 9) ? b3[r15] : 0.0f;

    // stage W1 (fp32)
    for (int idx = tid; idx < 1152; idx += 256) W1_lds[idx] = W1[idx];

    // triplet features (rows clamped at batch edges; garbage rows never gathered)
    if (tid < ROWS) {
        int i = j0 - 2 + tid;
        i = (i < 0) ? 0 : ((i > Nn - 3) ? (Nn - 3) : i);
        const float* base = y + ((size_t)b * Nn + i) * 6;
        float xp0 = base[0],  xp1 = base[1],  xp2 = base[2];
        float xm0 = base[6],  xm1 = base[7],  xm2 = base[8];
        float xn0 = base[12], xn1 = base[13], xn2 = base[14];
        float off = atan2f(xm1 - xp1, xm0 - xp0);
        t_lds[tid][0] = xp2 - off;
        t_lds[tid][1] = xm2 - off;
        t_lds[tid][2] = xn2 - off;
        t_lds[tid][3] = xp0;
        t_lds[tid][4] = xp1;
        t_lds[tid][5] = xm0;
        t_lds[tid][6] = xm1;
        t_lds[tid][7] = xn0;
        t_lds[tid][8] = xn1;
    }
    __syncthreads();

    // ---- layer 1: fp32 VALU, 4 threads/row x 32 cols ----
    {
        int r = tid >> 2, cq = tid & 3;
        float acc1[32];
        #pragma unroll
        for (int cc = 0; cc < 32; ++cc) acc1[cc] = 0.0f;
        #pragma unroll
        for (int k = 0; k < 9; ++k) {
            float tk = t_lds[r][k];
            const float* wrow = &W1_lds[k * 128 + cq * 32];
            #pragma unroll
            for (int cc = 0; cc < 32; ++cc) acc1[cc] += tk * wrow[cc];
        }
        char* hb = h1_raw + r * 256;
        int swz = (r & 7) << 4;
        #pragma unroll
        for (int cc = 0; cc < 32; cc += 2) {
            int c = cq * 32 + cc;
            float v0 = swish(acc1[cc] + b1[c]);
            float v1 = swish(acc1[cc + 1] + b1[c + 1]);
            unsigned int pk = f2bf(v0) | (f2bf(v1) << 16);
            *(unsigned int*)(hb + ((2 * c) ^ swz)) = pk;
        }
    }
    __syncthreads();

    // ---- layer 2: MFMA 16x16x32, wave owns cols [32w,32w+32) ----
    f32x4 acc[4][2];
    #pragma unroll
    for (int rt = 0; rt < 4; ++rt)
        #pragma unroll
        for (int ct = 0; ct < 2; ++ct)
            acc[rt][ct] = (f32x4)0.0f;

    #pragma unroll
    for (int rt = 0; rt < 4; ++rt) {
        int row = rt * 16 + r15;
        const char* hb = h1_raw + row * 256;
        int swz = (row & 7) << 4;
        short8 a[4];
        #pragma unroll
        for (int ks = 0; ks < 4; ++ks)
            a[ks] = *(const short8*)(hb + ((ks * 64 + g * 16) ^ swz));
        #pragma unroll
        for (int ct = 0; ct < 2; ++ct)
            #pragma unroll
            for (int ks = 0; ks < 4; ++ks)
                acc[rt][ct] = __builtin_amdgcn_mfma_f32_16x16x32_bf16(
                    a[ks], b2f[ct][ks], acc[rt][ct], 0, 0, 0);
    }
    // epilogue: bias + swish -> h2 (bf16, swizzled)
    #pragma unroll
    for (int rt = 0; rt < 4; ++rt)
        #pragma unroll
        for (int ct = 0; ct < 2; ++ct) {
            int col = w * 32 + ct * 16 + r15;
            #pragma unroll
            for (int e = 0; e < 4; ++e) {
                int row = rt * 16 + g * 4 + e;
                float v = swish(acc[rt][ct][e] + b2v[ct]);
                *(unsigned short*)(h2_raw + row * 256 + ((2 * col) ^ ((row & 7) << 4)))
                    = (unsigned short)f2bf(v);
            }
        }
    __syncthreads();

    // ---- layer 3: MFMA, wave owns rows [16w,16w+16), cols 0..8 (padded 16) ----
    {
        f32x4 facc = (f32x4)0.0f;
        int row = w * 16 + r15;
        const char* hb = h2_raw + row * 256;
        int swz = (row & 7) << 4;
        #pragma unroll
        for (int ks = 0; ks < 4; ++ks) {
            short8 a = *(const short8*)(hb + ((ks * 64 + g * 16) ^ swz));
            facc = __builtin_amdgcn_mfma_f32_16x16x32_bf16(a, b3f[ks], facc, 0, 0, 0);
        }
        if (r15 < 9) {
            #pragma unroll
            for (int e = 0; e < 4; ++e)
                f_lds[w * 16 + g * 4 + e][r15] = facc[e] + b3v;
        }
    }
    __syncthreads();

    // ---- gather: res[b][j] = fP(j)[3,4,0] + fM(j-1)[5,6,1] + fN(j-2)[7,8,2] ----
    if (tid < 3 * JOUT) {
        int jo = tid / 3, c = tid - jo * 3;
        int j = j0 + jo;
        if (j < Nn) {
            float val = 0.0f;
            if (j != 0 && j != Nn - 1) {
                int cP = (c == 0) ? 3 : (c == 1) ? 4 : 0;
                int cM = (c == 0) ? 5 : (c == 1) ? 6 : 1;
                int cN = (c == 0) ? 7 : (c == 1) ? 8 : 2;
                if (j <= Nn - 3) val += f_lds[jo + 2][cP];   // i = j   (always r in range)
                val += f_lds[jo + 1][cM];                    // i = j-1 (valid: 1<=j<=N-2)
                if (j >= 2) val += f_lds[jo][cN];            // i = j-2
            }
            out[((size_t)b * Nn + j) * 3 + c] = val;
        }
    }
}

extern "C" void kernel_launch(void* const* d_in, const int* in_sizes, int n_in,
                              void* d_out, int out_size, void* d_ws, size_t ws_size,
                              hipStream_t stream)
{
    const float* y  = (const float*)d_in[0];
    const float* W1 = (const float*)d_in[1];
    const float* b1 = (const float*)d_in[2];
    const float* W2 = (const float*)d_in[3];
    const float* b2 = (const float*)d_in[4];
    const float* W3 = (const float*)d_in[5];
    const float* b3 = (const float*)d_in[6];
    unsigned short* ws = (unsigned short*)d_ws;   // needs 36864 B
    float* out = (float*)d_out;

    prep_kernel<<<72, 256, 0, stream>>>(W2, W3, ws);
    dim3 grid(NBJ, Bn);
    fused_kernel<<<grid, 256, 0, stream>>>(y, W1, b1, b2, b3, ws, out);
}

// Round 2
// 131.815 us; speedup vs baseline: 1.2724x; 1.2724x over previous
//
#include <hip/hip_runtime.h>
#include <hip/hip_bf16.h>

#define Bn 128
#define Nn 8192
#define Hn 128
#define ROWS 64
#define JOUT 62
#define NBJ 133   // ceil(8192/62)

typedef __attribute__((ext_vector_type(8))) short short8;
typedef __attribute__((ext_vector_type(4))) float f32x4;
typedef __attribute__((ext_vector_type(4))) unsigned int u32x4;

__device__ __forceinline__ unsigned int f2bf(float x) {
    union { float f; unsigned u; } v; v.f = x;
    return (v.u + 0x7fffu + ((v.u >> 16) & 1u)) >> 16;
}
__device__ __forceinline__ float swish(float x) {
    return x * __builtin_amdgcn_rcpf(1.0f + __expf(-x));
}

// Pre-pack W2/W3 as bf16 MFMA fragments into ws.
// ws2 (0..16383): frag F = ((w*2+ct)*4+ks), lane l, elem e:
//   m-col = w*32+ct*16+(l&15), k = ks*32 + (l>>4)*8 + e  -> W2[k][col]
//   (used as the A-operand of the swapped layer-2 mfma)
// ws3 (16384..18431): per-wave layer-3 B-frag, frag w, lane l, elem e:
//   k-map matches layer-2 C layout: k = 32w + (e>>2)*16 + (l>>4)*4 + (e&3)
//   col = l&15 (<9 else 0)                                -> W3[k][col]
__global__ void prep_kernel(const float* __restrict__ W2, const float* __restrict__ W3,
                            unsigned short* __restrict__ ws)
{
    int tid = blockIdx.x * 256 + threadIdx.x;
    if (tid < 16384) {
        int F = tid >> 9, rem = tid & 511;
        int l = rem >> 3, e = rem & 7;
        int w = F >> 3, ct = (F >> 2) & 1, ks = F & 3;
        int col = w * 32 + ct * 16 + (l & 15);
        int k = ks * 32 + (l >> 4) * 8 + e;
        ws[tid] = (unsigned short)f2bf(W2[k * Hn + col]);
    } else if (tid < 18432) {
        int t2 = tid - 16384;
        int w = t2 >> 9, rem = t2 & 511;
        int l = rem >> 3, e = rem & 7;
        int c = l & 15;
        int k = 32 * w + ((e >> 2) << 4) + ((l >> 4) << 2) + (e & 3);
        float v = (c < 9) ? W3[k * 9 + c] : 0.0f;
        ws[tid] = (unsigned short)f2bf(v);
    }
}

__global__ __launch_bounds__(256, 4) void fused_kernel(
    const float* __restrict__ y, const float* __restrict__ W1,
    const float* __restrict__ b1, const float* __restrict__ b2,
    const float* __restrict__ b3, const unsigned short* __restrict__ ws,
    float* __restrict__ out)
{
    __shared__ char h1_raw[ROWS * 256];     // bf16, XOR-swizzled rows
    __shared__ float f_lds[4][ROWS][12];    // per-wave layer-3 K-partials

    const int tid = threadIdx.x;
    const int lane = tid & 63;
    const int w = tid >> 6;
    const int wu = __builtin_amdgcn_readfirstlane(w);
    const int b = blockIdx.y;
    const int j0 = blockIdx.x * JOUT;
    const int r15 = lane & 15, g = lane >> 4;

    // ---- triplet features, per-lane row (each wave recomputes; no LDS) ----
    float t[9];
    {
        int i = j0 - 2 + lane;
        i = (i < 0) ? 0 : ((i > Nn - 3) ? (Nn - 3) : i);
        const float* base = y + ((size_t)b * Nn + i) * 6;
        float xp0 = base[0],  xp1 = base[1],  xp2 = base[2];
        float xm0 = base[6],  xm1 = base[7],  xm2 = base[8];
        float xn0 = base[12], xn1 = base[13], xn2 = base[14];
        float off = atan2f(xm1 - xp1, xm0 - xp0);
        t[0] = xp2 - off; t[1] = xm2 - off; t[2] = xn2 - off;
        t[3] = xp0; t[4] = xp1; t[5] = xm0; t[6] = xm1; t[7] = xn0; t[8] = xn1;
    }

    // ---- layer 1: fp32 VALU; W1/b1 via wave-uniform scalar loads ----
    {
        const float* W1w = W1 + (wu << 5);
        const float* b1w = b1 + (wu << 5);
        float acc1[32];
        #pragma unroll
        for (int cc = 0; cc < 32; ++cc) acc1[cc] = b1w[cc];
        #pragma unroll
        for (int k = 0; k < 9; ++k) {
            float tk = t[k];
            const float* wr = W1w + k * Hn;
            #pragma unroll
            for (int cc = 0; cc < 32; ++cc) acc1[cc] = fmaf(tk, wr[cc], acc1[cc]);
        }
        // swish -> bf16 pack -> swizzled b128 writes (row = lane, cols 32w..32w+31)
        char* hb = h1_raw + lane * 256;
        const int swz = (lane & 7) << 4;
        #pragma unroll
        for (int q = 0; q < 4; ++q) {
            u32x4 pk;
            #pragma unroll
            for (int d = 0; d < 4; ++d) {
                float v0 = swish(acc1[q * 8 + 2 * d]);
                float v1 = swish(acc1[q * 8 + 2 * d + 1]);
                pk[d] = f2bf(v0) | (f2bf(v1) << 16);
            }
            *(u32x4*)(hb + (((wu << 6) + (q << 4)) ^ swz)) = pk;
        }
    }
    __syncthreads();

    // ---- layer 2 (swapped): h2^T[ct][nt] = W2^T-frag x h1^T-frag ----
    const short8* wsf = (const short8*)ws;
    short8 a2[2][4];
    #pragma unroll
    for (int ct = 0; ct < 2; ++ct)
        #pragma unroll
        for (int ks = 0; ks < 4; ++ks)
            a2[ct][ks] = wsf[((w * 2 + ct) * 4 + ks) * 64 + lane];

    f32x4 acc2[2][4];
    #pragma unroll
    for (int ct = 0; ct < 2; ++ct)
        #pragma unroll
        for (int nt = 0; nt < 4; ++nt)
            acc2[ct][nt] = (f32x4)0.0f;

    #pragma unroll
    for (int nt = 0; nt < 4; ++nt) {
        int row = nt * 16 + r15;
        const char* hr = h1_raw + row * 256;
        int sz = (row & 7) << 4;
        #pragma unroll
        for (int ks = 0; ks < 4; ++ks) {
            short8 hfrag = *(const short8*)(hr + ((ks * 64 + g * 16) ^ sz));
            acc2[0][nt] = __builtin_amdgcn_mfma_f32_16x16x32_bf16(a2[0][ks], hfrag, acc2[0][nt], 0, 0, 0);
            acc2[1][nt] = __builtin_amdgcn_mfma_f32_16x16x32_bf16(a2[1][ks], hfrag, acc2[1][nt], 0, 0, 0);
        }
    }

    // ---- epilogue: bias + swish -> bf16 A3-frags, all in registers ----
    // lane holds h2[row = nt*16+r15][col = 32w + (e'>>2)*16 + g*4 + (e'&3)]
    float b2v[8];
    #pragma unroll
    for (int h = 0; h < 2; ++h) {
        const float* bp = b2 + (w << 5) + (h << 4) + (g << 2);
        #pragma unroll
        for (int d = 0; d < 4; ++d) b2v[h * 4 + d] = bp[d];
    }
    short8 pa[4];
    #pragma unroll
    for (int nt = 0; nt < 4; ++nt) {
        union { unsigned int u[4]; short8 s; } pk;
        #pragma unroll
        for (int h = 0; h < 2; ++h)
            #pragma unroll
            for (int d = 0; d < 4; d += 2) {
                float v0 = swish(acc2[h][nt][d]     + b2v[h * 4 + d]);
                float v1 = swish(acc2[h][nt][d + 1] + b2v[h * 4 + d + 1]);
                pk.u[h * 2 + d / 2] = f2bf(v0) | (f2bf(v1) << 16);
            }
        pa[nt] = pk.s;
    }

    // ---- layer 3: per-wave K=32 partial via register-resident MFMA ----
    {
        short8 b3f = wsf[2048 + w * 64 + lane];
        #pragma unroll
        for (int nt = 0; nt < 4; ++nt) {
            f32x4 fp = __builtin_amdgcn_mfma_f32_16x16x32_bf16(pa[nt], b3f, (f32x4)0.0f, 0, 0, 0);
            if (r15 < 9) {
                #pragma unroll
                for (int e = 0; e < 4; ++e)
                    f_lds[w][nt * 16 + g * 4 + e][r15] = fp[e];
            }
        }
    }
    __syncthreads();

    // ---- gather: sum 4 wave-partials + b3, 3-tap stencil ----
    if (tid < 3 * JOUT) {
        int jo = tid / 3, c = tid - jo * 3;
        int j = j0 + jo;
        if (j < Nn) {
            float val = 0.0f;
            if (j != 0 && j != Nn - 1) {
                int cP = (c == 0) ? 3 : (c == 1) ? 4 : 0;
                int cM = (c == 0) ? 5 : (c == 1) ? 6 : 1;
                int cN = (c == 0) ? 7 : (c == 1) ? 8 : 2;
                if (j <= Nn - 3)
                    val += f_lds[0][jo + 2][cP] + f_lds[1][jo + 2][cP]
                         + f_lds[2][jo + 2][cP] + f_lds[3][jo + 2][cP] + b3[cP];
                val += f_lds[0][jo + 1][cM] + f_lds[1][jo + 1][cM]
                     + f_lds[2][jo + 1][cM] + f_lds[3][jo + 1][cM] + b3[cM];
                if (j >= 2)
                    val += f_lds[0][jo][cN] + f_lds[1][jo][cN]
                         + f_lds[2][jo][cN] + f_lds[3][jo][cN] + b3[cN];
            }
            out[((size_t)b * Nn + j) * 3 + c] = val;
        }
    }
}

extern "C" void kernel_launch(void* const* d_in, const int* in_sizes, int n_in,
                              void* d_out, int out_size, void* d_ws, size_t ws_size,
                              hipStream_t stream)
{
    const float* y  = (const float*)d_in[0];
    const float* W1 = (const float*)d_in[1];
    const float* b1 = (const float*)d_in[2];
    const float* W2 = (const float*)d_in[3];
    const float* b2 = (const float*)d_in[4];
    const float* W3 = (const float*)d_in[5];
    const float* b3 = (const float*)d_in[6];
    unsigned short* ws = (unsigned short*)d_ws;   // needs 36864 B
    float* out = (float*)d_out;

    prep_kernel<<<72, 256, 0, stream>>>(W2, W3, ws);
    dim3 grid(NBJ, Bn);
    fused_kernel<<<grid, 256, 0, stream>>>(y, W1, b1, b2, b3, ws, out);
}

// Round 3
// 117.386 us; speedup vs baseline: 1.4288x; 1.1229x over previous
//
#include <hip/hip_runtime.h>
#include <hip/hip_bf16.h>

#define Bn 128
#define Nn 8192
#define Hn 128
#define JOUT 62
#define NBJ 133   // ceil(8192/62)

typedef __attribute__((ext_vector_type(8))) short short8;
typedef __attribute__((ext_vector_type(4))) float f32x4;
typedef __attribute__((ext_vector_type(4))) unsigned int u32x4;

__device__ __forceinline__ unsigned short f2bf(float x) {
    union { float f; unsigned u; } v; v.f = x;
    return (unsigned short)((v.u + 0x7fffu + ((v.u >> 16) & 1u)) >> 16);
}
__device__ __forceinline__ float bf2f(unsigned short h) {
    union { unsigned u; float f; } v; v.u = ((unsigned)h) << 16;
    return v.f;
}
__device__ __forceinline__ unsigned short flo(float x) {   // low bf16 correction
    return f2bf(x - bf2f(f2bf(x)));
}
__device__ __forceinline__ float swish(float x) {
    return x * __builtin_amdgcn_rcpf(1.0f + __expf(-x));
}
// compiler-cast pair pack -> v_cvt_pk_bf16_f32 (m240: do NOT hand-roll)
__device__ __forceinline__ unsigned pk2(float a, float b) {
    union { __hip_bfloat16 h; unsigned short u; } ca, cb;
    ca.h = __float2bfloat16(a); cb.h = __float2bfloat16(b);
    return (unsigned)ca.u | ((unsigned)cb.u << 16);
}

// ws (unsigned short, 22528 elems = 45056 B):
//  [0      .. 4095 ]  8  A1-frags (W1 hi/lo + b1 folded), frag mt: m=16mt+(l&15)
//  [4096   .. 20479] 32  A2-frags (W2, k-map kappa), frag (mt2*4+ks)
//  [20480  .. 22527]  4  B3-frags (W3, k-map kappa), frag ks
// kappa(ks, p) = 16*(2ks + ((p&7)>>2)) + 4*(p>>3) + (p&3),  p = slot (l>>4)*8+e
__global__ void prep_kernel(const float* __restrict__ W1, const float* __restrict__ b1,
                            const float* __restrict__ W2, const float* __restrict__ W3,
                            unsigned short* __restrict__ ws)
{
    int tid = blockIdx.x * 256 + threadIdx.x;
    if (tid >= 22528) return;
    int f = tid >> 9, r = tid & 511;
    int l = r >> 3, e = r & 7;
    int p = ((l >> 4) << 3) | e;
    int c16 = l & 15;
    unsigned short v = 0;
    if (f < 8) {
        int col = (f << 4) | c16;
        if (p < 9)        v = f2bf(W1[p * Hn + col]);        // pairs t_hi
        else if (p < 18)  v = flo(W1[(p - 9) * Hn + col]);   // pairs t_hi
        else if (p < 27)  v = f2bf(W1[(p - 18) * Hn + col]); // pairs t_lo
        else if (p == 27) v = f2bf(b1[col]);                 // pairs 1.0
        else if (p == 28) v = flo(b1[col]);                  // pairs 1.0
    } else if (f < 40) {
        int mt2 = (f - 8) >> 2, ks = (f - 8) & 3;
        int col = (mt2 << 4) | c16;
        int k = 16 * (2 * ks + ((p & 7) >> 2)) + ((p >> 3) << 2) + (p & 3);
        v = f2bf(W2[k * Hn + col]);
    } else {
        int ks = f - 40;
        int k = 16 * (2 * ks + ((p & 7) >> 2)) + ((p >> 3) << 2) + (p & 3);
        if (c16 < 9) v = f2bf(W3[k * 9 + c16]);
    }
    ws[tid] = v;
}

__global__ __launch_bounds__(256, 4) void fused_kernel(
    const float* __restrict__ y, const float* __restrict__ b2g,
    const float* __restrict__ b3, const unsigned short* __restrict__ ws,
    float* __restrict__ out)
{
    __shared__ __align__(16) char tb[64 * 80];   // per-row 32-slot bf16 k-vector (stride 80B: 2-way banks)
    __shared__ float f_lds[64][12];

    const int tid = threadIdx.x;
    const int lane = tid & 63;
    const int w = tid >> 6;
    const int b = blockIdx.y;
    const int j0 = blockIdx.x * JOUT;
    const int r15 = lane & 15, g = lane >> 4;

    const short8* wsf = (const short8*)ws;

    // fragment loads (issue early; L1/L2-resident after first blocks)
    short8 w1f[8];
    #pragma unroll
    for (int mt = 0; mt < 8; ++mt) w1f[mt] = wsf[mt * 64 + lane];
    short8 b3f[4];
    #pragma unroll
    for (int ks = 0; ks < 4; ++ks) b3f[ks] = wsf[2560 + ks * 64 + lane];

    // ---- wave 0: triplet features -> hi/lo k-vectors in LDS ----
    if (tid < 64) {
        int i = j0 - 2 + tid;
        i = (i < 0) ? 0 : ((i > Nn - 3) ? (Nn - 3) : i);
        const float* base = y + ((size_t)b * Nn + i) * 6;
        float xp0 = base[0],  xp1 = base[1],  xp2 = base[2];
        float xm0 = base[6],  xm1 = base[7],  xm2 = base[8];
        float xn0 = base[12], xn1 = base[13], xn2 = base[14];
        float off = atan2f(xm1 - xp1, xm0 - xp0);
        float t0 = xp2 - off, t1 = xm2 - off, t2 = xn2 - off;
        unsigned short h0 = f2bf(t0), h1 = f2bf(t1), h2 = f2bf(t2);
        unsigned short h3 = f2bf(xp0), h4 = f2bf(xp1), h5 = f2bf(xm0);
        unsigned short h6 = f2bf(xm1), h7 = f2bf(xn0), h8 = f2bf(xn1);
        unsigned short l0 = f2bf(t0 - bf2f(h0)), l1 = f2bf(t1 - bf2f(h1));
        unsigned short l2 = f2bf(t2 - bf2f(h2)), l3 = f2bf(xp0 - bf2f(h3));
        unsigned short l4 = f2bf(xp1 - bf2f(h4)), l5 = f2bf(xm0 - bf2f(h5));
        unsigned short l6 = f2bf(xm1 - bf2f(h6)), l7 = f2bf(xn0 - bf2f(h7));
        unsigned short l8 = f2bf(xn1 - bf2f(h8));
        #define PK(a,bv) ((unsigned)(a) | ((unsigned)(bv) << 16))
        u32x4 v0 = { PK(h0,h1), PK(h2,h3), PK(h4,h5), PK(h6,h7) };         // slots 0..7
        u32x4 v1 = { PK(h8,h0), PK(h1,h2), PK(h3,h4), PK(h5,h6) };         // slots 8..15
        u32x4 v2 = { PK(h7,h8), PK(l0,l1), PK(l2,l3), PK(l4,l5) };         // slots 16..23
        u32x4 v3 = { PK(l6,l7), PK(l8,0x3F80u), PK(0x3F80u,0u), 0u };      // slots 24..31
        #undef PK
        char* dst = tb + tid * 80;
        *(u32x4*)(dst)      = v0;
        *(u32x4*)(dst + 16) = v1;
        *(u32x4*)(dst + 32) = v2;
        *(u32x4*)(dst + 48) = v3;
    }
    __syncthreads();

    // ---- layer 1: 8 MFMAs (A=W1 frags, B=t k-vector), fp32-accurate via hi/lo ----
    short8 tf = *(const short8*)(tb + (16 * w + r15) * 80 + g * 16);
    f32x4 acc1[8];
    #pragma unroll
    for (int mt = 0; mt < 8; ++mt)
        acc1[mt] = __builtin_amdgcn_mfma_f32_16x16x32_bf16(w1f[mt], tf, (f32x4)0.0f, 0, 0, 0);

    // swish -> bf16 B2-frags (kappa makes frag ks = [acc1[2ks], acc1[2ks+1]])
    short8 b2f[4];
    #pragma unroll
    for (int ks = 0; ks < 4; ++ks) {
        union { unsigned u[4]; short8 s; } pk;
        pk.u[0] = pk2(swish(acc1[2 * ks][0]),     swish(acc1[2 * ks][1]));
        pk.u[1] = pk2(swish(acc1[2 * ks][2]),     swish(acc1[2 * ks][3]));
        pk.u[2] = pk2(swish(acc1[2 * ks + 1][0]), swish(acc1[2 * ks + 1][1]));
        pk.u[3] = pk2(swish(acc1[2 * ks + 1][2]), swish(acc1[2 * ks + 1][3]));
        b2f[ks] = pk.s;
    }

    // ---- layer 2: stream A2-frags, 4-MFMA K=128 chain per h2col-tile ----
    unsigned a3u[4][4];
    #pragma unroll
    for (int mt2 = 0; mt2 < 8; ++mt2) {
        short8 a2f0 = wsf[512 + (mt2 * 4 + 0) * 64 + lane];
        short8 a2f1 = wsf[512 + (mt2 * 4 + 1) * 64 + lane];
        short8 a2f2 = wsf[512 + (mt2 * 4 + 2) * 64 + lane];
        short8 a2f3 = wsf[512 + (mt2 * 4 + 3) * 64 + lane];
        f32x4 acc = __builtin_amdgcn_mfma_f32_16x16x32_bf16(a2f0, b2f[0], (f32x4)0.0f, 0, 0, 0);
        acc = __builtin_amdgcn_mfma_f32_16x16x32_bf16(a2f1, b2f[1], acc, 0, 0, 0);
        acc = __builtin_amdgcn_mfma_f32_16x16x32_bf16(a2f2, b2f[2], acc, 0, 0, 0);
        acc = __builtin_amdgcn_mfma_f32_16x16x32_bf16(a2f3, b2f[3], acc, 0, 0, 0);
        const f32x4 bias = *(const f32x4*)(b2g + mt2 * 16 + 4 * g);
        float s0 = swish(acc[0] + bias[0]);
        float s1 = swish(acc[1] + bias[1]);
        float s2 = swish(acc[2] + bias[2]);
        float s3 = swish(acc[3] + bias[3]);
        a3u[mt2 >> 1][(mt2 & 1) * 2 + 0] = pk2(s0, s1);
        a3u[mt2 >> 1][(mt2 & 1) * 2 + 1] = pk2(s2, s3);
    }

    // ---- layer 3: 4 MFMAs (A=h2 frags in-register, B=W3 frags) ----
    {
        union { unsigned u[4]; short8 s; } c0, c1, c2, c3;
        #pragma unroll
        for (int q = 0; q < 4; ++q) { c0.u[q] = a3u[0][q]; c1.u[q] = a3u[1][q];
                                      c2.u[q] = a3u[2][q]; c3.u[q] = a3u[3][q]; }
        f32x4 f01 = __builtin_amdgcn_mfma_f32_16x16x32_bf16(c0.s, b3f[0], (f32x4)0.0f, 0, 0, 0);
        f01 = __builtin_amdgcn_mfma_f32_16x16x32_bf16(c1.s, b3f[1], f01, 0, 0, 0);
        f32x4 f23 = __builtin_amdgcn_mfma_f32_16x16x32_bf16(c2.s, b3f[2], (f32x4)0.0f, 0, 0, 0);
        f23 = __builtin_amdgcn_mfma_f32_16x16x32_bf16(c3.s, b3f[3], f23, 0, 0, 0);
        f32x4 fa = f01 + f23;
        if (r15 < 9) {
            #pragma unroll
            for (int e = 0; e < 4; ++e)
                f_lds[16 * w + 4 * g + e][r15] = fa[e];
        }
    }
    __syncthreads();

    // ---- gather: 3-tap stencil, boundaries zeroed ----
    if (tid < 3 * JOUT) {
        int jo = tid / 3, c = tid - jo * 3;
        int j = j0 + jo;
        if (j < Nn) {
            float val = 0.0f;
            if (j != 0 && j != Nn - 1) {
                int cP = (c == 0) ? 3 : (c == 1) ? 4 : 0;
                int cM = (c == 0) ? 5 : (c == 1) ? 6 : 1;
                int cN = (c == 0) ? 7 : (c == 1) ? 8 : 2;
                if (j <= Nn - 3) val += f_lds[jo + 2][cP] + b3[cP];   // i = j
                val += f_lds[jo + 1][cM] + b3[cM];                    // i = j-1
                if (j >= 2) val += f_lds[jo][cN] + b3[cN];            // i = j-2
            }
            out[((size_t)b * Nn + j) * 3 + c] = val;
        }
    }
}

extern "C" void kernel_launch(void* const* d_in, const int* in_sizes, int n_in,
                              void* d_out, int out_size, void* d_ws, size_t ws_size,
                              hipStream_t stream)
{
    const float* y  = (const float*)d_in[0];
    const float* W1 = (const float*)d_in[1];
    const float* b1 = (const float*)d_in[2];
    const float* W2 = (const float*)d_in[3];
    const float* b2 = (const float*)d_in[4];
    const float* W3 = (const float*)d_in[5];
    const float* b3 = (const float*)d_in[6];
    unsigned short* ws = (unsigned short*)d_ws;   // needs 45056 B
    float* out = (float*)d_out;

    prep_kernel<<<88, 256, 0, stream>>>(W1, b1, W2, W3, ws);
    dim3 grid(NBJ, Bn);
    fused_kernel<<<grid, 256, 0, stream>>>(y, b2, b3, ws, out);
}

// Round 4
// 106.803 us; speedup vs baseline: 1.5703x; 1.0991x over previous
//
#include <hip/hip_runtime.h>
#include <hip/hip_bf16.h>

#define Bn 128
#define Nn 8192
#define Hn 128
#define RPB 128
#define JOUT 126
#define NBJ 66    // ceil(8192/126)

typedef __attribute__((ext_vector_type(8))) short short8;
typedef __attribute__((ext_vector_type(4))) float f32x4;
typedef __attribute__((ext_vector_type(4))) unsigned int u32x4;

__device__ __forceinline__ unsigned short f2bf(float x) {
    union { float f; unsigned u; } v; v.f = x;
    return (unsigned short)((v.u + 0x7fffu + ((v.u >> 16) & 1u)) >> 16);
}
__device__ __forceinline__ float bf2f(unsigned short h) {
    union { unsigned u; float f; } v; v.u = ((unsigned)h) << 16;
    return v.f;
}
__device__ __forceinline__ unsigned short flo(float x) {   // low bf16 correction
    return f2bf(x - bf2f(f2bf(x)));
}
__device__ __forceinline__ float swish(float x) {
    return x * __builtin_amdgcn_rcpf(1.0f + __expf(-x));
}
// compiler-cast pair pack (compiler emits v_cvt_pk_bf16_f32; m240: don't hand-roll)
__device__ __forceinline__ unsigned pk2(float a, float b) {
    union { __hip_bfloat16 h; unsigned short u; } ca, cb;
    ca.h = __float2bfloat16(a); cb.h = __float2bfloat16(b);
    return (unsigned)ca.u | ((unsigned)cb.u << 16);
}

// ws (unsigned short, 22528 elems = 45056 B):
//  [0      .. 4095 ]  8  A1-frags (W1 hi/lo + b1 folded), frag mt: m=16mt+(l&15)
//  [4096   .. 20479] 32  A2-frags (W2, k-map kappa), frag (mt2*4+ks)
//  [20480  .. 22527]  4  B3-frags (W3, k-map kappa), frag ks
// kappa(ks, p) = 16*(2ks + ((p&7)>>2)) + 4*(p>>3) + (p&3),  p = slot (l>>4)*8+e
__global__ void prep_kernel(const float* __restrict__ W1, const float* __restrict__ b1,
                            const float* __restrict__ W2, const float* __restrict__ W3,
                            unsigned short* __restrict__ ws)
{
    int tid = blockIdx.x * 256 + threadIdx.x;
    if (tid >= 22528) return;
    int f = tid >> 9, r = tid & 511;
    int l = r >> 3, e = r & 7;
    int p = ((l >> 4) << 3) | e;
    int c16 = l & 15;
    unsigned short v = 0;
    if (f < 8) {
        int col = (f << 4) | c16;
        if (p < 9)        v = f2bf(W1[p * Hn + col]);        // pairs t_hi
        else if (p < 18)  v = flo(W1[(p - 9) * Hn + col]);   // pairs t_hi
        else if (p < 27)  v = f2bf(W1[(p - 18) * Hn + col]); // pairs t_lo
        else if (p == 27) v = f2bf(b1[col]);                 // pairs 1.0
        else if (p == 28) v = flo(b1[col]);                  // pairs 1.0
    } else if (f < 40) {
        int mt2 = (f - 8) >> 2, ks = (f - 8) & 3;
        int col = (mt2 << 4) | c16;
        int k = 16 * (2 * ks + ((p & 7) >> 2)) + ((p >> 3) << 2) + (p & 3);
        v = f2bf(W2[k * Hn + col]);
    } else {
        int ks = f - 40;
        int k = 16 * (2 * ks + ((p & 7) >> 2)) + ((p >> 3) << 2) + (p & 3);
        if (c16 < 9) v = f2bf(W3[k * 9 + c16]);
    }
    ws[tid] = v;
}

__global__ __launch_bounds__(256, 4) void fused_kernel(
    const float* __restrict__ y, const float* __restrict__ b2g,
    const float* __restrict__ b3, const unsigned short* __restrict__ ws,
    float* __restrict__ out)
{
    __shared__ __align__(16) char tb[RPB * 80];  // per-row 32-slot bf16 k-vector, stride 80B
    __shared__ float f_lds[RPB][12];

    const int tid = threadIdx.x;
    const int lane = tid & 63;
    const int w = tid >> 6;
    const int b = blockIdx.y;
    const int j0 = blockIdx.x * JOUT;
    const int r15 = lane & 15, g = lane >> 4;

    const short8* wsf = (const short8*)ws;

    // ---- triplet features: 128 threads, one row each -> hi/lo k-vectors in LDS ----
    if (tid < RPB) {
        int i = j0 - 2 + tid;
        i = (i < 0) ? 0 : ((i > Nn - 3) ? (Nn - 3) : i);
        const float* base = y + ((size_t)b * Nn + i) * 6;
        float xp0 = base[0],  xp1 = base[1],  xp2 = base[2];
        float xm0 = base[6],  xm1 = base[7],  xm2 = base[8];
        float xn0 = base[12], xn1 = base[13], xn2 = base[14];
        float off = atan2f(xm1 - xp1, xm0 - xp0);
        float t0 = xp2 - off, t1 = xm2 - off, t2 = xn2 - off;
        unsigned short h0 = f2bf(t0), h1 = f2bf(t1), h2 = f2bf(t2);
        unsigned short h3 = f2bf(xp0), h4 = f2bf(xp1), h5 = f2bf(xm0);
        unsigned short h6 = f2bf(xm1), h7 = f2bf(xn0), h8 = f2bf(xn1);
        unsigned short l0 = f2bf(t0 - bf2f(h0)), l1 = f2bf(t1 - bf2f(h1));
        unsigned short l2 = f2bf(t2 - bf2f(h2)), l3 = f2bf(xp0 - bf2f(h3));
        unsigned short l4 = f2bf(xp1 - bf2f(h4)), l5 = f2bf(xm0 - bf2f(h5));
        unsigned short l6 = f2bf(xm1 - bf2f(h6)), l7 = f2bf(xn0 - bf2f(h7));
        unsigned short l8 = f2bf(xn1 - bf2f(h8));
        #define PK(a,bv) ((unsigned)(a) | ((unsigned)(bv) << 16))
        u32x4 v0 = { PK(h0,h1), PK(h2,h3), PK(h4,h5), PK(h6,h7) };         // slots 0..7
        u32x4 v1 = { PK(h8,h0), PK(h1,h2), PK(h3,h4), PK(h5,h6) };         // slots 8..15
        u32x4 v2 = { PK(h7,h8), PK(l0,l1), PK(l2,l3), PK(l4,l5) };         // slots 16..23
        u32x4 v3 = { PK(l6,l7), PK(l8,0x3F80u), PK(0x3F80u,0u), 0u };      // slots 24..31
        #undef PK
        char* dst = tb + tid * 80;
        *(u32x4*)(dst)      = v0;
        *(u32x4*)(dst + 16) = v1;
        *(u32x4*)(dst + 32) = v2;
        *(u32x4*)(dst + 48) = v3;
    }
    __syncthreads();

    // ---- layer 1: per row-tile nt, 8 MFMAs (A=W1 frags, B=t k-vec), hi/lo fp32 ----
    short8 b2f[2][4];
    {
        short8 w1f[8];
        #pragma unroll
        for (int mt = 0; mt < 8; ++mt) w1f[mt] = wsf[mt * 64 + lane];
        #pragma unroll
        for (int nt = 0; nt < 2; ++nt) {
            short8 tf = *(const short8*)(tb + (32 * w + 16 * nt + r15) * 80 + g * 16);
            f32x4 acc1[8];
            #pragma unroll
            for (int mt = 0; mt < 8; ++mt)
                acc1[mt] = __builtin_amdgcn_mfma_f32_16x16x32_bf16(w1f[mt], tf, (f32x4)0.0f, 0, 0, 0);
            #pragma unroll
            for (int ks = 0; ks < 4; ++ks) {
                union { unsigned u[4]; short8 s; } pk;
                pk.u[0] = pk2(swish(acc1[2 * ks][0]),     swish(acc1[2 * ks][1]));
                pk.u[1] = pk2(swish(acc1[2 * ks][2]),     swish(acc1[2 * ks][3]));
                pk.u[2] = pk2(swish(acc1[2 * ks + 1][0]), swish(acc1[2 * ks + 1][1]));
                pk.u[3] = pk2(swish(acc1[2 * ks + 1][2]), swish(acc1[2 * ks + 1][3]));
                b2f[nt][ks] = pk.s;
            }
        }
    }

    // ---- layer 2: stream A2-frags once, apply to both row-tiles (2:1 density) ----
    unsigned a3u[2][4][4];
    #pragma unroll
    for (int mt2 = 0; mt2 < 8; ++mt2) {
        short8 a2f0 = wsf[512 + (mt2 * 4 + 0) * 64 + lane];
        short8 a2f1 = wsf[512 + (mt2 * 4 + 1) * 64 + lane];
        short8 a2f2 = wsf[512 + (mt2 * 4 + 2) * 64 + lane];
        short8 a2f3 = wsf[512 + (mt2 * 4 + 3) * 64 + lane];
        const f32x4 bias = *(const f32x4*)(b2g + mt2 * 16 + 4 * g);
        #pragma unroll
        for (int nt = 0; nt < 2; ++nt) {
            f32x4 acc = __builtin_amdgcn_mfma_f32_16x16x32_bf16(a2f0, b2f[nt][0], (f32x4)0.0f, 0, 0, 0);
            acc = __builtin_amdgcn_mfma_f32_16x16x32_bf16(a2f1, b2f[nt][1], acc, 0, 0, 0);
            acc = __builtin_amdgcn_mfma_f32_16x16x32_bf16(a2f2, b2f[nt][2], acc, 0, 0, 0);
            acc = __builtin_amdgcn_mfma_f32_16x16x32_bf16(a2f3, b2f[nt][3], acc, 0, 0, 0);
            float s0 = swish(acc[0] + bias[0]);
            float s1 = swish(acc[1] + bias[1]);
            float s2 = swish(acc[2] + bias[2]);
            float s3 = swish(acc[3] + bias[3]);
            a3u[nt][mt2 >> 1][(mt2 & 1) * 2 + 0] = pk2(s0, s1);
            a3u[nt][mt2 >> 1][(mt2 & 1) * 2 + 1] = pk2(s2, s3);
        }
    }

    // ---- layer 3: per row-tile, 4 register-resident MFMAs ----
    {
        short8 b3f[4];
        #pragma unroll
        for (int ks = 0; ks < 4; ++ks) b3f[ks] = wsf[2560 + ks * 64 + lane];
        float b3v = (r15 < 9) ? b3[r15] : 0.0f;
        #pragma unroll
        for (int nt = 0; nt < 2; ++nt) {
            union { unsigned u[4]; short8 s; } c0, c1, c2, c3;
            #pragma unroll
            for (int q = 0; q < 4; ++q) {
                c0.u[q] = a3u[nt][0][q]; c1.u[q] = a3u[nt][1][q];
                c2.u[q] = a3u[nt][2][q]; c3.u[q] = a3u[nt][3][q];
            }
            f32x4 f01 = __builtin_amdgcn_mfma_f32_16x16x32_bf16(c0.s, b3f[0], (f32x4)0.0f, 0, 0, 0);
            f01 = __builtin_amdgcn_mfma_f32_16x16x32_bf16(c1.s, b3f[1], f01, 0, 0, 0);
            f32x4 f23 = __builtin_amdgcn_mfma_f32_16x16x32_bf16(c2.s, b3f[2], (f32x4)0.0f, 0, 0, 0);
            f23 = __builtin_amdgcn_mfma_f32_16x16x32_bf16(c3.s, b3f[3], f23, 0, 0, 0);
            f32x4 fa = f01 + f23;
            if (r15 < 9) {
                #pragma unroll
                for (int e = 0; e < 4; ++e)
                    f_lds[32 * w + 16 * nt + 4 * g + e][r15] = fa[e] + b3v;
            }
        }
    }
    __syncthreads();

    // ---- gather: 3-tap stencil, boundaries zeroed (378 outputs, strided loop) ----
    for (int o = tid; o < 3 * JOUT; o += 256) {
        int jo = o / 3, c = o - jo * 3;
        int j = j0 + jo;
        if (j < Nn) {
            float val = 0.0f;
            if (j != 0 && j != Nn - 1) {
                int cP = (c == 0) ? 3 : (c == 1) ? 4 : 0;
                int cM = (c == 0) ? 5 : (c == 1) ? 6 : 1;
                int cN = (c == 0) ? 7 : (c == 1) ? 8 : 2;
                if (j <= Nn - 3) val += f_lds[jo + 2][cP];   // i = j
                val += f_lds[jo + 1][cM];                    // i = j-1
                if (j >= 2) val += f_lds[jo][cN];            // i = j-2
            }
            out[((size_t)b * Nn + j) * 3 + c] = val;
        }
    }
}

extern "C" void kernel_launch(void* const* d_in, const int* in_sizes, int n_in,
                              void* d_out, int out_size, void* d_ws, size_t ws_size,
                              hipStream_t stream)
{
    const float* y  = (const float*)d_in[0];
    const float* W1 = (const float*)d_in[1];
    const float* b1 = (const float*)d_in[2];
    const float* W2 = (const float*)d_in[3];
    const float* b2 = (const float*)d_in[4];
    const float* W3 = (const float*)d_in[5];
    const float* b3 = (const float*)d_in[6];
    unsigned short* ws = (unsigned short*)d_ws;   // needs 45056 B
    float* out = (float*)d_out;

    prep_kernel<<<88, 256, 0, stream>>>(W1, b1, W2, W3, ws);
    dim3 grid(NBJ, Bn);
    fused_kernel<<<grid, 256, 0, stream>>>(y, b2, b3, ws, out);
}